// Round 2
// baseline (1347.341 us; speedup 1.0000x reference)
//
#include <hip/hip_runtime.h>

// ---------------------------------------------------------------------------
// GIN block: h = MLP(x + segment_sum(x[src], dst)); MLP = Lin-ReLU-BN-Lin-ReLU-BN
// Pipeline:
//   k_init        : h0 = x (accumulator init) + zero stats region
//   k_scatter     : h0[dst] += x[src]  (atomic fp32, 16 thr/edge, float4 loads)
//   k_gemm<64>    : h1 = ReLU(h0 @ W1 + b1)        (fp32 vector FMA, LDS tiles)
//   k_col_stats   : column sum/sumsq of h1         (BN1 stats)
//   k_bn_fold     : fold BN1 affine into W2',b2'   (W2' = a1.W2, b2' = b2 + c1@W2)
//   k_gemm<128>   : out = ReLU(h1 @ W2' + b2')
//   k_col_stats   : column stats of out            (BN2 stats)
//   k_bn_coeffs   : a2,c2
//   k_bn_apply    : out = a2*out + c2
// Round-1 delta: GEMM column blocking tx*8 -> {tx*4, 64+tx*4} so the two
// ds_read_b128 of sW per k are 2-way (free) instead of 4-way bank conflicts.
// ---------------------------------------------------------------------------

__global__ __launch_bounds__(256) void k_init(const float* __restrict__ x,
                                              float* __restrict__ h0,
                                              float* __restrict__ stats,
                                              long n4)
{
    long i = (long)blockIdx.x * 256 + threadIdx.x;
    if (blockIdx.x == 0) {
        stats[threadIdx.x]       = 0.f;   // sum1/sq1/sum2/sq2 = 512 floats
        stats[threadIdx.x + 256] = 0.f;
    }
    if (i < n4) ((float4*)h0)[i] = ((const float4*)x)[i];
}

__global__ __launch_bounds__(256) void k_scatter(const int* __restrict__ ei,
                                                 const float* __restrict__ x,
                                                 float* __restrict__ h0,
                                                 int E)
{
    long t = (long)blockIdx.x * 256 + threadIdx.x;
    long total = (long)E * 16;
    if (t >= total) return;
    int e    = (int)(t >> 4);
    int lane = (int)(t & 15);
    int src = ei[e];
    int dst = ei[E + e];
    float4 v = ((const float4*)(x + (long)src * 64))[lane];
    float* p = h0 + (long)dst * 64 + lane * 4;
    atomicAdd(p + 0, v.x);
    atomicAdd(p + 1, v.y);
    atomicAdd(p + 2, v.z);
    atomicAdd(p + 3, v.w);
}

// Tiled fp32 GEMM: Out[N x 128] = ReLU(A[N x K] @ W[K x 128] + bias)
// Block: 256 threads, 64-row tile, full 128-col width.
// thread (ty,tx): rows ty*4..+3, cols {tx*4..+3} and {64+tx*4..+3}.
// A staged transposed in LDS so the per-k fragment read is one ds_read_b128.
template<int K>
__global__ __launch_bounds__(256) void k_gemm_bias_relu(
    const float* __restrict__ A, const float* __restrict__ W,
    const float* __restrict__ bias, float* __restrict__ Out, int N)
{
    __shared__ float sAT[64][72];    // [k][row], pad 72 to break bank aliasing
    __shared__ float sW[64][128];    // [k][col]

    const int tid = threadIdx.x;
    const int tx = tid & 15;         // col group
    const int ty = tid >> 4;         // row group
    const int row0 = blockIdx.x * 64;

    float acc[4][8];
#pragma unroll
    for (int i = 0; i < 4; ++i)
#pragma unroll
        for (int j = 0; j < 8; ++j) acc[i][j] = 0.f;

    for (int k0 = 0; k0 < K; k0 += 64) {
        // stage A^T tile: 64 rows x 64 k  (1024 float4, 4 per thread)
#pragma unroll
        for (int ch = 0; ch < 4; ++ch) {
            int idx = ch * 256 + tid;
            int r = idx >> 4, kq = idx & 15;
            int grow = row0 + r;
            float4 v = make_float4(0.f, 0.f, 0.f, 0.f);
            if (grow < N) v = *(const float4*)(A + (long)grow * K + (k0 + kq * 4));
            sAT[kq * 4 + 0][r] = v.x;
            sAT[kq * 4 + 1][r] = v.y;
            sAT[kq * 4 + 2][r] = v.z;
            sAT[kq * 4 + 3][r] = v.w;
        }
        // stage W tile: 64 k x 128 cols (2048 float4, 8 per thread)
#pragma unroll
        for (int ch = 0; ch < 8; ++ch) {
            int idx = ch * 256 + tid;
            int kr = idx >> 5, cq = idx & 31;
            *(float4*)(&sW[kr][cq * 4]) = *(const float4*)(W + (long)(k0 + kr) * 128 + cq * 4);
        }
        __syncthreads();

#pragma unroll 8
        for (int k = 0; k < 64; ++k) {
            float4 av = *(const float4*)(&sAT[k][ty * 4]);
            float4 w0 = *(const float4*)(&sW[k][tx * 4]);        // 2-way (free)
            float4 w1 = *(const float4*)(&sW[k][64 + tx * 4]);   // 2-way (free)
            float a[4] = {av.x, av.y, av.z, av.w};
            float w[8] = {w0.x, w0.y, w0.z, w0.w, w1.x, w1.y, w1.z, w1.w};
#pragma unroll
            for (int i = 0; i < 4; ++i)
#pragma unroll
                for (int j = 0; j < 8; ++j)
                    acc[i][j] = fmaf(a[i], w[j], acc[i][j]);
        }
        __syncthreads();
    }

    float b[8];
#pragma unroll
    for (int j = 0; j < 4; ++j) b[j] = bias[tx * 4 + j];
#pragma unroll
    for (int j = 0; j < 4; ++j) b[4 + j] = bias[64 + tx * 4 + j];

#pragma unroll
    for (int i = 0; i < 4; ++i) {
        int grow = row0 + ty * 4 + i;
        if (grow < N) {
            float4 o0, o1;
            o0.x = fmaxf(acc[i][0] + b[0], 0.f);
            o0.y = fmaxf(acc[i][1] + b[1], 0.f);
            o0.z = fmaxf(acc[i][2] + b[2], 0.f);
            o0.w = fmaxf(acc[i][3] + b[3], 0.f);
            o1.x = fmaxf(acc[i][4] + b[4], 0.f);
            o1.y = fmaxf(acc[i][5] + b[5], 0.f);
            o1.z = fmaxf(acc[i][6] + b[6], 0.f);
            o1.w = fmaxf(acc[i][7] + b[7], 0.f);
            *(float4*)(Out + (long)grow * 128 + tx * 4)      = o0;
            *(float4*)(Out + (long)grow * 128 + 64 + tx * 4) = o1;
        }
    }
}

__global__ __launch_bounds__(256) void k_col_stats(const float* __restrict__ H, int N,
                                                   float* __restrict__ sums,
                                                   float* __restrict__ sqs)
{
    int c = threadIdx.x & 127;
    int half = threadIdx.x >> 7;
    float s = 0.f, q = 0.f;
    for (long r = (long)blockIdx.x * 2 + half; r < N; r += (long)gridDim.x * 2) {
        float v = H[r * 128 + c];
        s += v;
        q = fmaf(v, v, q);
    }
    __shared__ float ls[256], lq[256];
    ls[threadIdx.x] = s;
    lq[threadIdx.x] = q;
    __syncthreads();
    if (threadIdx.x < 128) {
        atomicAdd(&sums[c], ls[threadIdx.x] + ls[threadIdx.x + 128]);
        atomicAdd(&sqs[c],  lq[threadIdx.x] + lq[threadIdx.x + 128]);
    }
}

// BN1 coefficients folded into GEMM2's weights:
//   a = g*rsqrt(var+eps); c = beta - mean*a
//   W2p[k][j] = a[k]*W2[k][j];  b2p[j] = b2[j] + sum_k c[k]*W2[k][j]
__global__ void k_bn_fold(const float* __restrict__ stats,
                          const float* __restrict__ gamma, const float* __restrict__ beta,
                          const float* __restrict__ W2, const float* __restrict__ b2,
                          float* __restrict__ W2p, float* __restrict__ b2p, float invN)
{
    __shared__ float as[128], cs[128];
    int j = threadIdx.x;
    float m = stats[j] * invN;
    float v = stats[128 + j] * invN - m * m;
    float a = gamma[j] * rsqrtf(v + 1e-5f);
    float c = beta[j] - m * a;
    as[j] = a;
    cs[j] = c;
    __syncthreads();
    float bb = b2[j];
    for (int k = 0; k < 128; ++k) {
        float w = W2[k * 128 + j];
        W2p[k * 128 + j] = as[k] * w;
        bb = fmaf(cs[k], w, bb);
    }
    b2p[j] = bb;
}

__global__ void k_bn_coeffs(const float* __restrict__ stats,
                            const float* __restrict__ gamma, const float* __restrict__ beta,
                            float* __restrict__ ac, float invN)
{
    int j = threadIdx.x;
    float m = stats[j] * invN;
    float v = stats[128 + j] * invN - m * m;
    float a = gamma[j] * rsqrtf(v + 1e-5f);
    ac[j] = a;
    ac[128 + j] = beta[j] - m * a;
}

__global__ __launch_bounds__(256) void k_bn_apply(float* __restrict__ out,
                                                  const float* __restrict__ ac, long n4)
{
    __shared__ float sa[128], sc[128];
    if (threadIdx.x < 128) {
        sa[threadIdx.x] = ac[threadIdx.x];
        sc[threadIdx.x] = ac[128 + threadIdx.x];
    }
    __syncthreads();
    long i = (long)blockIdx.x * 256 + threadIdx.x;
    if (i < n4) {
        float4 v = ((float4*)out)[i];
        int c0 = (int)((i * 4) & 127);
        v.x = fmaf(v.x, sa[c0 + 0], sc[c0 + 0]);
        v.y = fmaf(v.y, sa[c0 + 1], sc[c0 + 1]);
        v.z = fmaf(v.z, sa[c0 + 2], sc[c0 + 2]);
        v.w = fmaf(v.w, sa[c0 + 3], sc[c0 + 3]);
        ((float4*)out)[i] = v;
    }
}

extern "C" void kernel_launch(void* const* d_in, const int* in_sizes, int n_in,
                              void* d_out, int out_size, void* d_ws, size_t ws_size,
                              hipStream_t stream)
{
    const float* x   = (const float*)d_in[0];
    const int*   ei  = (const int*)  d_in[1];
    const float* W1  = (const float*)d_in[2];
    const float* b1  = (const float*)d_in[3];
    const float* g1  = (const float*)d_in[4];
    const float* be1 = (const float*)d_in[5];
    const float* W2  = (const float*)d_in[6];
    const float* b2  = (const float*)d_in[7];
    const float* g2  = (const float*)d_in[8];
    const float* be2 = (const float*)d_in[9];
    float* out = (float*)d_out;

    const int N = in_sizes[0] / 64;   // 100000
    const int E = in_sizes[1] / 2;    // 1250000

    // workspace layout (floats)
    float* ws    = (float*)d_ws;
    float* h0    = ws;                        // N*64
    float* h1    = h0 + (long)N * 64;         // N*128
    float* W2p   = h1 + (long)N * 128;        // 128*128
    float* b2p   = W2p + 128 * 128;           // 128
    float* stats = b2p + 128;                 // 512: sum1,sq1,sum2,sq2
    float* ac    = stats + 512;               // 256: a2,c2

    const float invN = 1.0f / (float)N;

    long n4h0 = (long)N * 64 / 4;
    int initBlocks = (int)((n4h0 + 255) / 256);
    k_init<<<initBlocks, 256, 0, stream>>>(x, h0, stats, n4h0);

    long scThreads = (long)E * 16;
    int scBlocks = (int)((scThreads + 255) / 256);
    k_scatter<<<scBlocks, 256, 0, stream>>>(ei, x, h0, E);

    int gBlocks = (N + 63) / 64;
    k_gemm_bias_relu<64><<<gBlocks, 256, 0, stream>>>(h0, W1, b1, h1, N);

    k_col_stats<<<512, 256, 0, stream>>>(h1, N, stats, stats + 128);

    k_bn_fold<<<1, 128, 0, stream>>>(stats, g1, be1, W2, b2, W2p, b2p, invN);

    k_gemm_bias_relu<128><<<gBlocks, 256, 0, stream>>>(h1, W2p, b2p, out, N);

    k_col_stats<<<512, 256, 0, stream>>>(out, N, stats + 256, stats + 384);

    k_bn_coeffs<<<1, 128, 0, stream>>>(stats + 256, g2, be2, ac, invN);

    long n4o = (long)N * 128 / 4;
    k_bn_apply<<<(int)((n4o + 255) / 256), 256, 0, stream>>>(out, ac, n4o);
}

// Round 3
// 785.501 us; speedup vs baseline: 1.7153x; 1.7153x over previous
//
#include <hip/hip_runtime.h>

// ---------------------------------------------------------------------------
// GIN block: h = MLP(x + segment_sum(x[src], dst)); MLP = Lin-ReLU-BN-Lin-ReLU-BN
// Round-2 delta: atomic fp32 scatter (1062us, atomic-bound, VALUBusy ~1%)
// replaced by CSR build (hist/scan/fill, int atomics only) + per-node gather
// (no atomics; x fits in L3 so row gathers are cache hits).
// Pipeline:
//   k_zero        : deg = 0, stats = 0
//   k_hist        : deg[dst]++                      (1.25M int atomics)
//   k_scan        : offs = exscan(deg); head = offs (single block)
//   k_fill        : nbr[head[dst]++] = src          (1.25M int atomics)
//   k_gather      : h0[n] = x[n] + sum_j x[nbr[j]]  (wave per node, lane=dim)
//   k_gemm<64>    : h1 = ReLU(h0 @ W1 + b1)
//   k_col_stats   : BN1 stats
//   k_bn_fold     : fold BN1 into W2',b2'
//   k_gemm<128>   : out = ReLU(h1 @ W2' + b2')
//   k_col_stats   : BN2 stats
//   k_bn_coeffs   : a2,c2
//   k_bn_apply    : out = a2*out + c2
// CSR arrays alias h1's region (dead before GEMM1 writes h1).
// ---------------------------------------------------------------------------

__global__ __launch_bounds__(256) void k_zero(int* __restrict__ deg,
                                              float* __restrict__ stats, int N)
{
    int i = blockIdx.x * 256 + threadIdx.x;
    if (i < N) deg[i] = 0;
    if (blockIdx.x == 0) {
        stats[threadIdx.x]       = 0.f;
        stats[threadIdx.x + 256] = 0.f;
    }
}

__global__ __launch_bounds__(256) void k_hist(const int* __restrict__ ei,
                                              int* __restrict__ deg, int E)
{
    int e = blockIdx.x * 256 + threadIdx.x;
    if (e < E) atomicAdd(&deg[ei[E + e]], 1);
}

// single-block exclusive scan of deg[0..N) -> offs, also head=offs, offs[N]=E
__global__ __launch_bounds__(1024) void k_scan(const int* __restrict__ deg,
                                               int* __restrict__ offs,
                                               int* __restrict__ head, int N, int E)
{
    __shared__ int part[1024];
    const int tid = threadIdx.x;
    const int per = (N + 1023) / 1024;
    const int base = tid * per;
    int s = 0;
    for (int i = 0; i < per; ++i) {
        int idx = base + i;
        if (idx < N) s += deg[idx];
    }
    part[tid] = s;
    __syncthreads();
    // Hillis-Steele inclusive scan over the 1024 partials
    for (int off = 1; off < 1024; off <<= 1) {
        int t = (tid >= off) ? part[tid - off] : 0;
        __syncthreads();
        part[tid] += t;
        __syncthreads();
    }
    int run = (tid == 0) ? 0 : part[tid - 1];   // exclusive prefix of this chunk
    for (int i = 0; i < per; ++i) {
        int idx = base + i;
        if (idx < N) {
            offs[idx] = run;
            head[idx] = run;
            run += deg[idx];
        }
    }
    if (tid == 1023) offs[N] = E;
}

__global__ __launch_bounds__(256) void k_fill(const int* __restrict__ ei,
                                              int* __restrict__ head,
                                              int* __restrict__ nbr, int E)
{
    int e = blockIdx.x * 256 + threadIdx.x;
    if (e < E) {
        int src = ei[e];
        int dst = ei[E + e];
        int slot = atomicAdd(&head[dst], 1);
        nbr[slot] = src;
    }
}

// wave per node, lane = feature dim (d_in = 64)
__global__ __launch_bounds__(256) void k_gather(const float* __restrict__ x,
                                                const int* __restrict__ offs,
                                                const int* __restrict__ nbr,
                                                float* __restrict__ h0, int N)
{
    int node = blockIdx.x * 4 + (threadIdx.x >> 6);
    int d = threadIdx.x & 63;
    if (node >= N) return;
    int b = offs[node], e = offs[node + 1];
    float acc = x[(long)node * 64 + d];
    for (int j = b; j < e; ++j) {
        int s = nbr[j];                       // wave-uniform (scalar) load
        acc += x[(long)s * 64 + d];           // 256B coalesced row read
    }
    h0[(long)node * 64 + d] = acc;
}

// Tiled fp32 GEMM: Out[N x 128] = ReLU(A[N x K] @ W[K x 128] + bias)
// Block: 256 threads, 64-row tile, full 128-col width.
// thread (ty,tx): rows ty*4..+3, cols {tx*4..+3} and {64+tx*4..+3}.
template<int K>
__global__ __launch_bounds__(256) void k_gemm_bias_relu(
    const float* __restrict__ A, const float* __restrict__ W,
    const float* __restrict__ bias, float* __restrict__ Out, int N)
{
    __shared__ float sAT[64][72];    // [k][row], pad 72 to break bank aliasing
    __shared__ float sW[64][128];    // [k][col]

    const int tid = threadIdx.x;
    const int tx = tid & 15;         // col group
    const int ty = tid >> 4;         // row group
    const int row0 = blockIdx.x * 64;

    float acc[4][8];
#pragma unroll
    for (int i = 0; i < 4; ++i)
#pragma unroll
        for (int j = 0; j < 8; ++j) acc[i][j] = 0.f;

    for (int k0 = 0; k0 < K; k0 += 64) {
#pragma unroll
        for (int ch = 0; ch < 4; ++ch) {
            int idx = ch * 256 + tid;
            int r = idx >> 4, kq = idx & 15;
            int grow = row0 + r;
            float4 v = make_float4(0.f, 0.f, 0.f, 0.f);
            if (grow < N) v = *(const float4*)(A + (long)grow * K + (k0 + kq * 4));
            sAT[kq * 4 + 0][r] = v.x;
            sAT[kq * 4 + 1][r] = v.y;
            sAT[kq * 4 + 2][r] = v.z;
            sAT[kq * 4 + 3][r] = v.w;
        }
#pragma unroll
        for (int ch = 0; ch < 8; ++ch) {
            int idx = ch * 256 + tid;
            int kr = idx >> 5, cq = idx & 31;
            *(float4*)(&sW[kr][cq * 4]) = *(const float4*)(W + (long)(k0 + kr) * 128 + cq * 4);
        }
        __syncthreads();

#pragma unroll 8
        for (int k = 0; k < 64; ++k) {
            float4 av = *(const float4*)(&sAT[k][ty * 4]);
            float4 w0 = *(const float4*)(&sW[k][tx * 4]);        // 2-way (free)
            float4 w1 = *(const float4*)(&sW[k][64 + tx * 4]);   // 2-way (free)
            float a[4] = {av.x, av.y, av.z, av.w};
            float w[8] = {w0.x, w0.y, w0.z, w0.w, w1.x, w1.y, w1.z, w1.w};
#pragma unroll
            for (int i = 0; i < 4; ++i)
#pragma unroll
                for (int j = 0; j < 8; ++j)
                    acc[i][j] = fmaf(a[i], w[j], acc[i][j]);
        }
        __syncthreads();
    }

    float b[8];
#pragma unroll
    for (int j = 0; j < 4; ++j) b[j] = bias[tx * 4 + j];
#pragma unroll
    for (int j = 0; j < 4; ++j) b[4 + j] = bias[64 + tx * 4 + j];

#pragma unroll
    for (int i = 0; i < 4; ++i) {
        int grow = row0 + ty * 4 + i;
        if (grow < N) {
            float4 o0, o1;
            o0.x = fmaxf(acc[i][0] + b[0], 0.f);
            o0.y = fmaxf(acc[i][1] + b[1], 0.f);
            o0.z = fmaxf(acc[i][2] + b[2], 0.f);
            o0.w = fmaxf(acc[i][3] + b[3], 0.f);
            o1.x = fmaxf(acc[i][4] + b[4], 0.f);
            o1.y = fmaxf(acc[i][5] + b[5], 0.f);
            o1.z = fmaxf(acc[i][6] + b[6], 0.f);
            o1.w = fmaxf(acc[i][7] + b[7], 0.f);
            *(float4*)(Out + (long)grow * 128 + tx * 4)      = o0;
            *(float4*)(Out + (long)grow * 128 + 64 + tx * 4) = o1;
        }
    }
}

__global__ __launch_bounds__(256) void k_col_stats(const float* __restrict__ H, int N,
                                                   float* __restrict__ sums,
                                                   float* __restrict__ sqs)
{
    int c = threadIdx.x & 127;
    int half = threadIdx.x >> 7;
    float s = 0.f, q = 0.f;
    for (long r = (long)blockIdx.x * 2 + half; r < N; r += (long)gridDim.x * 2) {
        float v = H[r * 128 + c];
        s += v;
        q = fmaf(v, v, q);
    }
    __shared__ float ls[256], lq[256];
    ls[threadIdx.x] = s;
    lq[threadIdx.x] = q;
    __syncthreads();
    if (threadIdx.x < 128) {
        atomicAdd(&sums[c], ls[threadIdx.x] + ls[threadIdx.x + 128]);
        atomicAdd(&sqs[c],  lq[threadIdx.x] + lq[threadIdx.x + 128]);
    }
}

// BN1 folded into GEMM2: a = g*rsqrt(var+eps); c = beta - mean*a
// W2p[k][j] = a[k]*W2[k][j];  b2p[j] = b2[j] + sum_k c[k]*W2[k][j]
__global__ void k_bn_fold(const float* __restrict__ stats,
                          const float* __restrict__ gamma, const float* __restrict__ beta,
                          const float* __restrict__ W2, const float* __restrict__ b2,
                          float* __restrict__ W2p, float* __restrict__ b2p, float invN)
{
    __shared__ float as[128], cs[128];
    int j = threadIdx.x;
    float m = stats[j] * invN;
    float v = stats[128 + j] * invN - m * m;
    float a = gamma[j] * rsqrtf(v + 1e-5f);
    float c = beta[j] - m * a;
    as[j] = a;
    cs[j] = c;
    __syncthreads();
    float bb = b2[j];
    for (int k = 0; k < 128; ++k) {
        float w = W2[k * 128 + j];
        W2p[k * 128 + j] = as[k] * w;
        bb = fmaf(cs[k], w, bb);
    }
    b2p[j] = bb;
}

__global__ void k_bn_coeffs(const float* __restrict__ stats,
                            const float* __restrict__ gamma, const float* __restrict__ beta,
                            float* __restrict__ ac, float invN)
{
    int j = threadIdx.x;
    float m = stats[j] * invN;
    float v = stats[128 + j] * invN - m * m;
    float a = gamma[j] * rsqrtf(v + 1e-5f);
    ac[j] = a;
    ac[128 + j] = beta[j] - m * a;
}

__global__ __launch_bounds__(256) void k_bn_apply(float* __restrict__ out,
                                                  const float* __restrict__ ac, long n4)
{
    __shared__ float sa[128], sc[128];
    if (threadIdx.x < 128) {
        sa[threadIdx.x] = ac[threadIdx.x];
        sc[threadIdx.x] = ac[128 + threadIdx.x];
    }
    __syncthreads();
    long i = (long)blockIdx.x * 256 + threadIdx.x;
    if (i < n4) {
        float4 v = ((float4*)out)[i];
        int c0 = (int)((i * 4) & 127);
        v.x = fmaf(v.x, sa[c0 + 0], sc[c0 + 0]);
        v.y = fmaf(v.y, sa[c0 + 1], sc[c0 + 1]);
        v.z = fmaf(v.z, sa[c0 + 2], sc[c0 + 2]);
        v.w = fmaf(v.w, sa[c0 + 3], sc[c0 + 3]);
        ((float4*)out)[i] = v;
    }
}

extern "C" void kernel_launch(void* const* d_in, const int* in_sizes, int n_in,
                              void* d_out, int out_size, void* d_ws, size_t ws_size,
                              hipStream_t stream)
{
    const float* x   = (const float*)d_in[0];
    const int*   ei  = (const int*)  d_in[1];
    const float* W1  = (const float*)d_in[2];
    const float* b1  = (const float*)d_in[3];
    const float* g1  = (const float*)d_in[4];
    const float* be1 = (const float*)d_in[5];
    const float* W2  = (const float*)d_in[6];
    const float* b2  = (const float*)d_in[7];
    const float* g2  = (const float*)d_in[8];
    const float* be2 = (const float*)d_in[9];
    float* out = (float*)d_out;

    const int N = in_sizes[0] / 64;   // 100000
    const int E = in_sizes[1] / 2;    // 1250000

    // workspace layout (floats)
    float* ws    = (float*)d_ws;
    float* h0    = ws;                        // N*64
    float* h1    = h0 + (long)N * 64;         // N*128
    float* W2p   = h1 + (long)N * 128;        // 128*128
    float* b2p   = W2p + 128 * 128;           // 128
    float* stats = b2p + 128;                 // 512: sum1,sq1,sum2,sq2
    float* ac    = stats + 512;               // 256: a2,c2

    // CSR arrays alias h1 (nbr dead before GEMM1 writes h1)
    int* deg  = (int*)h1;                     // N
    int* offs = deg + N;                      // N+1
    int* head = offs + N + 1;                 // N
    int* nbr  = head + N;                     // E

    const float invN = 1.0f / (float)N;

    k_zero<<<(N + 255) / 256, 256, 0, stream>>>(deg, stats, N);

    int eBlocks = (E + 255) / 256;
    k_hist<<<eBlocks, 256, 0, stream>>>(ei, deg, E);

    k_scan<<<1, 1024, 0, stream>>>(deg, offs, head, N, E);

    k_fill<<<eBlocks, 256, 0, stream>>>(ei, head, nbr, E);

    k_gather<<<(N + 3) / 4, 256, 0, stream>>>(x, offs, nbr, h0, N);

    int gBlocks = (N + 63) / 64;
    k_gemm_bias_relu<64><<<gBlocks, 256, 0, stream>>>(h0, W1, b1, h1, N);

    k_col_stats<<<512, 256, 0, stream>>>(h1, N, stats, stats + 128);

    k_bn_fold<<<1, 128, 0, stream>>>(stats, g1, be1, W2, b2, W2p, b2p, invN);

    k_gemm_bias_relu<128><<<gBlocks, 256, 0, stream>>>(h1, W2p, b2p, out, N);

    k_col_stats<<<512, 256, 0, stream>>>(out, N, stats + 256, stats + 384);

    k_bn_coeffs<<<1, 128, 0, stream>>>(stats + 256, g2, be2, ac, invN);

    long n4o = (long)N * 128 / 4;
    k_bn_apply<<<(int)((n4o + 255) / 256), 256, 0, stream>>>(out, ac, n4o);
}

// Round 4
// 539.621 us; speedup vs baseline: 2.4968x; 1.4557x over previous
//
#include <hip/hip_runtime.h>

// ---------------------------------------------------------------------------
// GIN block: h = MLP(x + segment_sum(x[src], dst)); MLP = Lin-ReLU-BN-Lin-ReLU-BN
// Round-3 delta: single-block k_scan (260us, 0.15% occupancy, latency-bound)
// replaced by two-level multi-block scan (scanA: chunk sums; scanB: scan of
// 98 partials; scanC: intra-chunk exclusive scan + offset). Rest unchanged.
// Pipeline:
//   k_zero        : deg = 0, stats = 0
//   k_hist        : deg[dst]++                      (1.25M int atomics)
//   k_scanA/B/C   : offs = exscan(deg); head = offs (multi-block)
//   k_fill        : nbr[head[dst]++] = src          (1.25M int atomics)
//   k_gather      : h0[n] = x[n] + sum_j x[nbr[j]]  (wave per node, lane=dim)
//   k_gemm<64>    : h1 = ReLU(h0 @ W1 + b1)
//   k_col_stats   : BN1 stats
//   k_bn_fold     : fold BN1 into W2',b2'
//   k_gemm<128>   : out = ReLU(h1 @ W2' + b2')
//   k_col_stats   : BN2 stats
//   k_bn_coeffs   : a2,c2
//   k_bn_apply    : out = a2*out + c2
// CSR arrays alias h1's region (dead before GEMM1 writes h1).
// ---------------------------------------------------------------------------

__global__ __launch_bounds__(256) void k_zero(int* __restrict__ deg,
                                              float* __restrict__ stats, int N)
{
    int i = blockIdx.x * 256 + threadIdx.x;
    if (i < N) deg[i] = 0;
    if (blockIdx.x == 0) {
        stats[threadIdx.x]       = 0.f;
        stats[threadIdx.x + 256] = 0.f;
    }
}

__global__ __launch_bounds__(256) void k_hist(const int* __restrict__ ei,
                                              int* __restrict__ deg, int E)
{
    int e = blockIdx.x * 256 + threadIdx.x;
    if (e < E) atomicAdd(&deg[ei[E + e]], 1);
}

// ---- two-level scan: 1024 elements per block ----
__global__ __launch_bounds__(256) void k_scanA(const int* __restrict__ deg,
                                               int* __restrict__ bsum, int N)
{
    int base = blockIdx.x * 1024 + threadIdx.x * 4;
    int s = 0;
    if (base + 3 < N) {
        int4 v = *(const int4*)(deg + base);
        s = v.x + v.y + v.z + v.w;
    } else {
#pragma unroll
        for (int i = 0; i < 4; ++i)
            if (base + i < N) s += deg[base + i];
    }
    __shared__ int ls[256];
    ls[threadIdx.x] = s;
    __syncthreads();
#pragma unroll
    for (int off = 128; off > 0; off >>= 1) {
        if (threadIdx.x < off) ls[threadIdx.x] += ls[threadIdx.x + off];
        __syncthreads();
    }
    if (threadIdx.x == 0) bsum[blockIdx.x] = ls[0];
}

// one block, up to 1024 chunk partials -> exclusive prefix
__global__ __launch_bounds__(1024) void k_scanB(const int* __restrict__ bsum,
                                                int* __restrict__ bpre,
                                                int* __restrict__ offs, int nb,
                                                int N, int E)
{
    __shared__ int ls[1024];
    int tid = threadIdx.x;
    int v = (tid < nb) ? bsum[tid] : 0;
    ls[tid] = v;
    __syncthreads();
    for (int off = 1; off < 1024; off <<= 1) {
        int t = (tid >= off) ? ls[tid - off] : 0;
        __syncthreads();
        ls[tid] += t;
        __syncthreads();
    }
    if (tid < nb) bpre[tid] = ls[tid] - v;   // exclusive
    if (tid == 0) offs[N] = E;
}

__global__ __launch_bounds__(256) void k_scanC(const int* __restrict__ deg,
                                               const int* __restrict__ bpre,
                                               int* __restrict__ offs,
                                               int* __restrict__ head, int N)
{
    int base = blockIdx.x * 1024 + threadIdx.x * 4;
    int v0 = 0, v1 = 0, v2 = 0, v3 = 0;
    if (base + 3 < N) {
        int4 v = *(const int4*)(deg + base);
        v0 = v.x; v1 = v.y; v2 = v.z; v3 = v.w;
    } else {
        if (base + 0 < N) v0 = deg[base + 0];
        if (base + 1 < N) v1 = deg[base + 1];
        if (base + 2 < N) v2 = deg[base + 2];
        if (base + 3 < N) v3 = deg[base + 3];
    }
    int s = v0 + v1 + v2 + v3;
    __shared__ int ls[256];
    int tid = threadIdx.x;
    ls[tid] = s;
    __syncthreads();
    for (int off = 1; off < 256; off <<= 1) {
        int t = (tid >= off) ? ls[tid - off] : 0;
        __syncthreads();
        ls[tid] += t;
        __syncthreads();
    }
    int run = bpre[blockIdx.x] + ls[tid] - s;   // exclusive prefix of this thread
    if (base + 0 < N) { offs[base + 0] = run; head[base + 0] = run; run += v0; }
    if (base + 1 < N) { offs[base + 1] = run; head[base + 1] = run; run += v1; }
    if (base + 2 < N) { offs[base + 2] = run; head[base + 2] = run; run += v2; }
    if (base + 3 < N) { offs[base + 3] = run; head[base + 3] = run; run += v3; }
}

__global__ __launch_bounds__(256) void k_fill(const int* __restrict__ ei,
                                              int* __restrict__ head,
                                              int* __restrict__ nbr, int E)
{
    int e = blockIdx.x * 256 + threadIdx.x;
    if (e < E) {
        int src = ei[e];
        int dst = ei[E + e];
        int slot = atomicAdd(&head[dst], 1);
        nbr[slot] = src;
    }
}

// wave per node, lane = feature dim (d_in = 64)
__global__ __launch_bounds__(256) void k_gather(const float* __restrict__ x,
                                                const int* __restrict__ offs,
                                                const int* __restrict__ nbr,
                                                float* __restrict__ h0, int N)
{
    int node = blockIdx.x * 4 + (threadIdx.x >> 6);
    int d = threadIdx.x & 63;
    if (node >= N) return;
    int b = offs[node], e = offs[node + 1];
    float acc = x[(long)node * 64 + d];
    for (int j = b; j < e; ++j) {
        int s = nbr[j];                       // wave-uniform load
        acc += x[(long)s * 64 + d];           // 256B coalesced row read
    }
    h0[(long)node * 64 + d] = acc;
}

// Tiled fp32 GEMM: Out[N x 128] = ReLU(A[N x K] @ W[K x 128] + bias)
template<int K>
__global__ __launch_bounds__(256) void k_gemm_bias_relu(
    const float* __restrict__ A, const float* __restrict__ W,
    const float* __restrict__ bias, float* __restrict__ Out, int N)
{
    __shared__ float sAT[64][72];    // [k][row], pad 72 to break bank aliasing
    __shared__ float sW[64][128];    // [k][col]

    const int tid = threadIdx.x;
    const int tx = tid & 15;         // col group
    const int ty = tid >> 4;         // row group
    const int row0 = blockIdx.x * 64;

    float acc[4][8];
#pragma unroll
    for (int i = 0; i < 4; ++i)
#pragma unroll
        for (int j = 0; j < 8; ++j) acc[i][j] = 0.f;

    for (int k0 = 0; k0 < K; k0 += 64) {
#pragma unroll
        for (int ch = 0; ch < 4; ++ch) {
            int idx = ch * 256 + tid;
            int r = idx >> 4, kq = idx & 15;
            int grow = row0 + r;
            float4 v = make_float4(0.f, 0.f, 0.f, 0.f);
            if (grow < N) v = *(const float4*)(A + (long)grow * K + (k0 + kq * 4));
            sAT[kq * 4 + 0][r] = v.x;
            sAT[kq * 4 + 1][r] = v.y;
            sAT[kq * 4 + 2][r] = v.z;
            sAT[kq * 4 + 3][r] = v.w;
        }
#pragma unroll
        for (int ch = 0; ch < 8; ++ch) {
            int idx = ch * 256 + tid;
            int kr = idx >> 5, cq = idx & 31;
            *(float4*)(&sW[kr][cq * 4]) = *(const float4*)(W + (long)(k0 + kr) * 128 + cq * 4);
        }
        __syncthreads();

#pragma unroll 8
        for (int k = 0; k < 64; ++k) {
            float4 av = *(const float4*)(&sAT[k][ty * 4]);
            float4 w0 = *(const float4*)(&sW[k][tx * 4]);        // 2-way (free)
            float4 w1 = *(const float4*)(&sW[k][64 + tx * 4]);   // 2-way (free)
            float a[4] = {av.x, av.y, av.z, av.w};
            float w[8] = {w0.x, w0.y, w0.z, w0.w, w1.x, w1.y, w1.z, w1.w};
#pragma unroll
            for (int i = 0; i < 4; ++i)
#pragma unroll
                for (int j = 0; j < 8; ++j)
                    acc[i][j] = fmaf(a[i], w[j], acc[i][j]);
        }
        __syncthreads();
    }

    float b[8];
#pragma unroll
    for (int j = 0; j < 4; ++j) b[j] = bias[tx * 4 + j];
#pragma unroll
    for (int j = 0; j < 4; ++j) b[4 + j] = bias[64 + tx * 4 + j];

#pragma unroll
    for (int i = 0; i < 4; ++i) {
        int grow = row0 + ty * 4 + i;
        if (grow < N) {
            float4 o0, o1;
            o0.x = fmaxf(acc[i][0] + b[0], 0.f);
            o0.y = fmaxf(acc[i][1] + b[1], 0.f);
            o0.z = fmaxf(acc[i][2] + b[2], 0.f);
            o0.w = fmaxf(acc[i][3] + b[3], 0.f);
            o1.x = fmaxf(acc[i][4] + b[4], 0.f);
            o1.y = fmaxf(acc[i][5] + b[5], 0.f);
            o1.z = fmaxf(acc[i][6] + b[6], 0.f);
            o1.w = fmaxf(acc[i][7] + b[7], 0.f);
            *(float4*)(Out + (long)grow * 128 + tx * 4)      = o0;
            *(float4*)(Out + (long)grow * 128 + 64 + tx * 4) = o1;
        }
    }
}

__global__ __launch_bounds__(256) void k_col_stats(const float* __restrict__ H, int N,
                                                   float* __restrict__ sums,
                                                   float* __restrict__ sqs)
{
    int c = threadIdx.x & 127;
    int half = threadIdx.x >> 7;
    float s = 0.f, q = 0.f;
    for (long r = (long)blockIdx.x * 2 + half; r < N; r += (long)gridDim.x * 2) {
        float v = H[r * 128 + c];
        s += v;
        q = fmaf(v, v, q);
    }
    __shared__ float ls[256], lq[256];
    ls[threadIdx.x] = s;
    lq[threadIdx.x] = q;
    __syncthreads();
    if (threadIdx.x < 128) {
        atomicAdd(&sums[c], ls[threadIdx.x] + ls[threadIdx.x + 128]);
        atomicAdd(&sqs[c],  lq[threadIdx.x] + lq[threadIdx.x + 128]);
    }
}

// BN1 folded into GEMM2: a = g*rsqrt(var+eps); c = beta - mean*a
__global__ void k_bn_fold(const float* __restrict__ stats,
                          const float* __restrict__ gamma, const float* __restrict__ beta,
                          const float* __restrict__ W2, const float* __restrict__ b2,
                          float* __restrict__ W2p, float* __restrict__ b2p, float invN)
{
    __shared__ float as[128], cs[128];
    int j = threadIdx.x;
    float m = stats[j] * invN;
    float v = stats[128 + j] * invN - m * m;
    float a = gamma[j] * rsqrtf(v + 1e-5f);
    float c = beta[j] - m * a;
    as[j] = a;
    cs[j] = c;
    __syncthreads();
    float bb = b2[j];
    for (int k = 0; k < 128; ++k) {
        float w = W2[k * 128 + j];
        W2p[k * 128 + j] = as[k] * w;
        bb = fmaf(cs[k], w, bb);
    }
    b2p[j] = bb;
}

__global__ void k_bn_coeffs(const float* __restrict__ stats,
                            const float* __restrict__ gamma, const float* __restrict__ beta,
                            float* __restrict__ ac, float invN)
{
    int j = threadIdx.x;
    float m = stats[j] * invN;
    float v = stats[128 + j] * invN - m * m;
    float a = gamma[j] * rsqrtf(v + 1e-5f);
    ac[j] = a;
    ac[128 + j] = beta[j] - m * a;
}

__global__ __launch_bounds__(256) void k_bn_apply(float* __restrict__ out,
                                                  const float* __restrict__ ac, long n4)
{
    __shared__ float sa[128], sc[128];
    if (threadIdx.x < 128) {
        sa[threadIdx.x] = ac[threadIdx.x];
        sc[threadIdx.x] = ac[128 + threadIdx.x];
    }
    __syncthreads();
    long i = (long)blockIdx.x * 256 + threadIdx.x;
    if (i < n4) {
        float4 v = ((float4*)out)[i];
        int c0 = (int)((i * 4) & 127);
        v.x = fmaf(v.x, sa[c0 + 0], sc[c0 + 0]);
        v.y = fmaf(v.y, sa[c0 + 1], sc[c0 + 1]);
        v.z = fmaf(v.z, sa[c0 + 2], sc[c0 + 2]);
        v.w = fmaf(v.w, sa[c0 + 3], sc[c0 + 3]);
        ((float4*)out)[i] = v;
    }
}

extern "C" void kernel_launch(void* const* d_in, const int* in_sizes, int n_in,
                              void* d_out, int out_size, void* d_ws, size_t ws_size,
                              hipStream_t stream)
{
    const float* x   = (const float*)d_in[0];
    const int*   ei  = (const int*)  d_in[1];
    const float* W1  = (const float*)d_in[2];
    const float* b1  = (const float*)d_in[3];
    const float* g1  = (const float*)d_in[4];
    const float* be1 = (const float*)d_in[5];
    const float* W2  = (const float*)d_in[6];
    const float* b2  = (const float*)d_in[7];
    const float* g2  = (const float*)d_in[8];
    const float* be2 = (const float*)d_in[9];
    float* out = (float*)d_out;

    const int N = in_sizes[0] / 64;   // 100000
    const int E = in_sizes[1] / 2;    // 1250000

    // workspace layout (floats)
    float* ws    = (float*)d_ws;
    float* h0    = ws;                        // N*64
    float* h1    = h0 + (long)N * 64;         // N*128
    float* W2p   = h1 + (long)N * 128;        // 128*128
    float* b2p   = W2p + 128 * 128;           // 128
    float* stats = b2p + 128;                 // 512: sum1,sq1,sum2,sq2
    float* ac    = stats + 512;               // 256: a2,c2

    // CSR arrays alias h1 (nbr dead before GEMM1 writes h1)
    int* deg  = (int*)h1;                     // N
    int* offs = deg + N;                      // N+1
    int* head = offs + N + 1;                 // N
    int* nbr  = head + N;                     // E
    int* bsum = nbr + E;                      // <=1024
    int* bpre = bsum + 1024;                  // <=1024

    const float invN = 1.0f / (float)N;
    const int nb = (N + 1023) / 1024;         // scan chunks

    k_zero<<<(N + 255) / 256, 256, 0, stream>>>(deg, stats, N);

    int eBlocks = (E + 255) / 256;
    k_hist<<<eBlocks, 256, 0, stream>>>(ei, deg, E);

    k_scanA<<<nb, 256, 0, stream>>>(deg, bsum, N);
    k_scanB<<<1, 1024, 0, stream>>>(bsum, bpre, offs, nb, N, E);
    k_scanC<<<nb, 256, 0, stream>>>(deg, bpre, offs, head, N);

    k_fill<<<eBlocks, 256, 0, stream>>>(ei, head, nbr, E);

    k_gather<<<(N + 3) / 4, 256, 0, stream>>>(x, offs, nbr, h0, N);

    int gBlocks = (N + 63) / 64;
    k_gemm_bias_relu<64><<<gBlocks, 256, 0, stream>>>(h0, W1, b1, h1, N);

    k_col_stats<<<512, 256, 0, stream>>>(h1, N, stats, stats + 128);

    k_bn_fold<<<1, 128, 0, stream>>>(stats, g1, be1, W2, b2, W2p, b2p, invN);

    k_gemm_bias_relu<128><<<gBlocks, 256, 0, stream>>>(h1, W2p, b2p, out, N);

    k_col_stats<<<512, 256, 0, stream>>>(out, N, stats + 256, stats + 384);

    k_bn_coeffs<<<1, 128, 0, stream>>>(stats + 256, g2, be2, ac, invN);

    long n4o = (long)N * 128 / 4;
    k_bn_apply<<<(int)((n4o + 255) / 256), 256, 0, stream>>>(out, ac, n4o);
}

// Round 6
// 479.684 us; speedup vs baseline: 2.8088x; 1.1250x over previous
//
#include <hip/hip_runtime.h>

// ---------------------------------------------------------------------------
// GIN block: h = MLP(x + segment_sum(x[src], dst)); MLP = Lin-ReLU-BN-Lin-ReLU-BN
// Round-4 delta (resubmitted round-5 after acquisition timeout):
// k_gather was latency-bound (122us, VALUBusy 13%, HBM 18%):
// one dependent 256B row-load chain per wave. Rework: 4x16-lane groups per
// wave, each walking a strided quarter of the edge list with float4 row
// segments (4 rows in flight per wave), then shfl_xor(16,32) cross-group
// reduction. 4x memory-level parallelism, iterations 12.5 -> ~3.2.
// Pipeline:
//   k_zero        : deg = 0, stats = 0
//   k_hist        : deg[dst]++                      (1.25M int atomics)
//   k_scanA/B/C   : offs = exscan(deg); head = offs (multi-block)
//   k_fill        : nbr[head[dst]++] = src          (1.25M int atomics)
//   k_gather      : h0[n] = x[n] + sum_j x[nbr[j]]  (wave per node, 4 edges in flight)
//   k_gemm<64>    : h1 = ReLU(h0 @ W1 + b1)
//   k_col_stats   : BN1 stats
//   k_bn_fold     : fold BN1 into W2',b2'
//   k_gemm<128>   : out = ReLU(h1 @ W2' + b2')
//   k_col_stats   : BN2 stats
//   k_bn_coeffs   : a2,c2
//   k_bn_apply    : out = a2*out + c2
// CSR arrays alias h1's region (dead before GEMM1 writes h1).
// ---------------------------------------------------------------------------

__global__ __launch_bounds__(256) void k_zero(int* __restrict__ deg,
                                              float* __restrict__ stats, int N)
{
    int i = blockIdx.x * 256 + threadIdx.x;
    if (i < N) deg[i] = 0;
    if (blockIdx.x == 0) {
        stats[threadIdx.x]       = 0.f;
        stats[threadIdx.x + 256] = 0.f;
    }
}

__global__ __launch_bounds__(256) void k_hist(const int* __restrict__ ei,
                                              int* __restrict__ deg, int E)
{
    int e = blockIdx.x * 256 + threadIdx.x;
    if (e < E) atomicAdd(&deg[ei[E + e]], 1);
}

// ---- two-level scan: 1024 elements per block ----
__global__ __launch_bounds__(256) void k_scanA(const int* __restrict__ deg,
                                               int* __restrict__ bsum, int N)
{
    int base = blockIdx.x * 1024 + threadIdx.x * 4;
    int s = 0;
    if (base + 3 < N) {
        int4 v = *(const int4*)(deg + base);
        s = v.x + v.y + v.z + v.w;
    } else {
#pragma unroll
        for (int i = 0; i < 4; ++i)
            if (base + i < N) s += deg[base + i];
    }
    __shared__ int ls[256];
    ls[threadIdx.x] = s;
    __syncthreads();
#pragma unroll
    for (int off = 128; off > 0; off >>= 1) {
        if (threadIdx.x < off) ls[threadIdx.x] += ls[threadIdx.x + off];
        __syncthreads();
    }
    if (threadIdx.x == 0) bsum[blockIdx.x] = ls[0];
}

// one block, up to 1024 chunk partials -> exclusive prefix
__global__ __launch_bounds__(1024) void k_scanB(const int* __restrict__ bsum,
                                                int* __restrict__ bpre,
                                                int* __restrict__ offs, int nb,
                                                int N, int E)
{
    __shared__ int ls[1024];
    int tid = threadIdx.x;
    int v = (tid < nb) ? bsum[tid] : 0;
    ls[tid] = v;
    __syncthreads();
    for (int off = 1; off < 1024; off <<= 1) {
        int t = (tid >= off) ? ls[tid - off] : 0;
        __syncthreads();
        ls[tid] += t;
        __syncthreads();
    }
    if (tid < nb) bpre[tid] = ls[tid] - v;   // exclusive
    if (tid == 0) offs[N] = E;
}

__global__ __launch_bounds__(256) void k_scanC(const int* __restrict__ deg,
                                               const int* __restrict__ bpre,
                                               int* __restrict__ offs,
                                               int* __restrict__ head, int N)
{
    int base = blockIdx.x * 1024 + threadIdx.x * 4;
    int v0 = 0, v1 = 0, v2 = 0, v3 = 0;
    if (base + 3 < N) {
        int4 v = *(const int4*)(deg + base);
        v0 = v.x; v1 = v.y; v2 = v.z; v3 = v.w;
    } else {
        if (base + 0 < N) v0 = deg[base + 0];
        if (base + 1 < N) v1 = deg[base + 1];
        if (base + 2 < N) v2 = deg[base + 2];
        if (base + 3 < N) v3 = deg[base + 3];
    }
    int s = v0 + v1 + v2 + v3;
    __shared__ int ls[256];
    int tid = threadIdx.x;
    ls[tid] = s;
    __syncthreads();
    for (int off = 1; off < 256; off <<= 1) {
        int t = (tid >= off) ? ls[tid - off] : 0;
        __syncthreads();
        ls[tid] += t;
        __syncthreads();
    }
    int run = bpre[blockIdx.x] + ls[tid] - s;   // exclusive prefix of this thread
    if (base + 0 < N) { offs[base + 0] = run; head[base + 0] = run; run += v0; }
    if (base + 1 < N) { offs[base + 1] = run; head[base + 1] = run; run += v1; }
    if (base + 2 < N) { offs[base + 2] = run; head[base + 2] = run; run += v2; }
    if (base + 3 < N) { offs[base + 3] = run; head[base + 3] = run; run += v3; }
}

__global__ __launch_bounds__(256) void k_fill(const int* __restrict__ ei,
                                              int* __restrict__ head,
                                              int* __restrict__ nbr, int E)
{
    int e = blockIdx.x * 256 + threadIdx.x;
    if (e < E) {
        int src = ei[e];
        int dst = ei[E + e];
        int slot = atomicAdd(&head[dst], 1);
        nbr[slot] = src;
    }
}

// wave per node; 4x16-lane groups each walk a strided quarter of the edge
// list with float4 row segments -> 4 rows in flight per wave.
__global__ __launch_bounds__(256) void k_gather(const float4* __restrict__ x4,
                                                const int* __restrict__ offs,
                                                const int* __restrict__ nbr,
                                                float4* __restrict__ h04, int N)
{
    int wid  = threadIdx.x >> 6;
    int lane = threadIdx.x & 63;
    int node = blockIdx.x * 4 + wid;
    if (node >= N) return;
    int d4 = lane & 15;                     // float4 slot within the 64-float row
    int g  = lane >> 4;                     // edge subgroup 0..3
    int b = offs[node], e = offs[node + 1];

    float4 acc = make_float4(0.f, 0.f, 0.f, 0.f);
    if (g == 0) acc = x4[(long)node * 16 + d4];   // self term in group 0

    for (int j = b + g; j < e; j += 4) {
        int s = nbr[j];                           // 16 lanes share one address
        float4 v = x4[(long)s * 16 + d4];         // 256B coalesced row segment
        acc.x += v.x; acc.y += v.y; acc.z += v.z; acc.w += v.w;
    }

    // reduce the 4 group partials (lanes with equal d4): xor 16 then 32
#pragma unroll
    for (int m = 16; m <= 32; m <<= 1) {
        acc.x += __shfl_xor(acc.x, m, 64);
        acc.y += __shfl_xor(acc.y, m, 64);
        acc.z += __shfl_xor(acc.z, m, 64);
        acc.w += __shfl_xor(acc.w, m, 64);
    }

    if (g == 0) h04[(long)node * 16 + d4] = acc;
}

// Tiled fp32 GEMM: Out[N x 128] = ReLU(A[N x K] @ W[K x 128] + bias)
template<int K>
__global__ __launch_bounds__(256) void k_gemm_bias_relu(
    const float* __restrict__ A, const float* __restrict__ W,
    const float* __restrict__ bias, float* __restrict__ Out, int N)
{
    __shared__ float sAT[64][72];    // [k][row], pad 72 to break bank aliasing
    __shared__ float sW[64][128];    // [k][col]

    const int tid = threadIdx.x;
    const int tx = tid & 15;         // col group
    const int ty = tid >> 4;         // row group
    const int row0 = blockIdx.x * 64;

    float acc[4][8];
#pragma unroll
    for (int i = 0; i < 4; ++i)
#pragma unroll
        for (int j = 0; j < 8; ++j) acc[i][j] = 0.f;

    for (int k0 = 0; k0 < K; k0 += 64) {
#pragma unroll
        for (int ch = 0; ch < 4; ++ch) {
            int idx = ch * 256 + tid;
            int r = idx >> 4, kq = idx & 15;
            int grow = row0 + r;
            float4 v = make_float4(0.f, 0.f, 0.f, 0.f);
            if (grow < N) v = *(const float4*)(A + (long)grow * K + (k0 + kq * 4));
            sAT[kq * 4 + 0][r] = v.x;
            sAT[kq * 4 + 1][r] = v.y;
            sAT[kq * 4 + 2][r] = v.z;
            sAT[kq * 4 + 3][r] = v.w;
        }
#pragma unroll
        for (int ch = 0; ch < 8; ++ch) {
            int idx = ch * 256 + tid;
            int kr = idx >> 5, cq = idx & 31;
            *(float4*)(&sW[kr][cq * 4]) = *(const float4*)(W + (long)(k0 + kr) * 128 + cq * 4);
        }
        __syncthreads();

#pragma unroll 8
        for (int k = 0; k < 64; ++k) {
            float4 av = *(const float4*)(&sAT[k][ty * 4]);
            float4 w0 = *(const float4*)(&sW[k][tx * 4]);        // 2-way (free)
            float4 w1 = *(const float4*)(&sW[k][64 + tx * 4]);   // 2-way (free)
            float a[4] = {av.x, av.y, av.z, av.w};
            float w[8] = {w0.x, w0.y, w0.z, w0.w, w1.x, w1.y, w1.z, w1.w};
#pragma unroll
            for (int i = 0; i < 4; ++i)
#pragma unroll
                for (int j = 0; j < 8; ++j)
                    acc[i][j] = fmaf(a[i], w[j], acc[i][j]);
        }
        __syncthreads();
    }

    float b[8];
#pragma unroll
    for (int j = 0; j < 4; ++j) b[j] = bias[tx * 4 + j];
#pragma unroll
    for (int j = 0; j < 4; ++j) b[4 + j] = bias[64 + tx * 4 + j];

#pragma unroll
    for (int i = 0; i < 4; ++i) {
        int grow = row0 + ty * 4 + i;
        if (grow < N) {
            float4 o0, o1;
            o0.x = fmaxf(acc[i][0] + b[0], 0.f);
            o0.y = fmaxf(acc[i][1] + b[1], 0.f);
            o0.z = fmaxf(acc[i][2] + b[2], 0.f);
            o0.w = fmaxf(acc[i][3] + b[3], 0.f);
            o1.x = fmaxf(acc[i][4] + b[4], 0.f);
            o1.y = fmaxf(acc[i][5] + b[5], 0.f);
            o1.z = fmaxf(acc[i][6] + b[6], 0.f);
            o1.w = fmaxf(acc[i][7] + b[7], 0.f);
            *(float4*)(Out + (long)grow * 128 + tx * 4)      = o0;
            *(float4*)(Out + (long)grow * 128 + 64 + tx * 4) = o1;
        }
    }
}

__global__ __launch_bounds__(256) void k_col_stats(const float* __restrict__ H, int N,
                                                   float* __restrict__ sums,
                                                   float* __restrict__ sqs)
{
    int c = threadIdx.x & 127;
    int half = threadIdx.x >> 7;
    float s = 0.f, q = 0.f;
    for (long r = (long)blockIdx.x * 2 + half; r < N; r += (long)gridDim.x * 2) {
        float v = H[r * 128 + c];
        s += v;
        q = fmaf(v, v, q);
    }
    __shared__ float ls[256], lq[256];
    ls[threadIdx.x] = s;
    lq[threadIdx.x] = q;
    __syncthreads();
    if (threadIdx.x < 128) {
        atomicAdd(&sums[c], ls[threadIdx.x] + ls[threadIdx.x + 128]);
        atomicAdd(&sqs[c],  lq[threadIdx.x] + lq[threadIdx.x + 128]);
    }
}

// BN1 folded into GEMM2: a = g*rsqrt(var+eps); c = beta - mean*a
__global__ void k_bn_fold(const float* __restrict__ stats,
                          const float* __restrict__ gamma, const float* __restrict__ beta,
                          const float* __restrict__ W2, const float* __restrict__ b2,
                          float* __restrict__ W2p, float* __restrict__ b2p, float invN)
{
    __shared__ float as[128], cs[128];
    int j = threadIdx.x;
    float m = stats[j] * invN;
    float v = stats[128 + j] * invN - m * m;
    float a = gamma[j] * rsqrtf(v + 1e-5f);
    float c = beta[j] - m * a;
    as[j] = a;
    cs[j] = c;
    __syncthreads();
    float bb = b2[j];
    for (int k = 0; k < 128; ++k) {
        float w = W2[k * 128 + j];
        W2p[k * 128 + j] = as[k] * w;
        bb = fmaf(cs[k], w, bb);
    }
    b2p[j] = bb;
}

__global__ void k_bn_coeffs(const float* __restrict__ stats,
                            const float* __restrict__ gamma, const float* __restrict__ beta,
                            float* __restrict__ ac, float invN)
{
    int j = threadIdx.x;
    float m = stats[j] * invN;
    float v = stats[128 + j] * invN - m * m;
    float a = gamma[j] * rsqrtf(v + 1e-5f);
    ac[j] = a;
    ac[128 + j] = beta[j] - m * a;
}

__global__ __launch_bounds__(256) void k_bn_apply(float* __restrict__ out,
                                                  const float* __restrict__ ac, long n4)
{
    __shared__ float sa[128], sc[128];
    if (threadIdx.x < 128) {
        sa[threadIdx.x] = ac[threadIdx.x];
        sc[threadIdx.x] = ac[128 + threadIdx.x];
    }
    __syncthreads();
    long i = (long)blockIdx.x * 256 + threadIdx.x;
    if (i < n4) {
        float4 v = ((float4*)out)[i];
        int c0 = (int)((i * 4) & 127);
        v.x = fmaf(v.x, sa[c0 + 0], sc[c0 + 0]);
        v.y = fmaf(v.y, sa[c0 + 1], sc[c0 + 1]);
        v.z = fmaf(v.z, sa[c0 + 2], sc[c0 + 2]);
        v.w = fmaf(v.w, sa[c0 + 3], sc[c0 + 3]);
        ((float4*)out)[i] = v;
    }
}

extern "C" void kernel_launch(void* const* d_in, const int* in_sizes, int n_in,
                              void* d_out, int out_size, void* d_ws, size_t ws_size,
                              hipStream_t stream)
{
    const float* x   = (const float*)d_in[0];
    const int*   ei  = (const int*)  d_in[1];
    const float* W1  = (const float*)d_in[2];
    const float* b1  = (const float*)d_in[3];
    const float* g1  = (const float*)d_in[4];
    const float* be1 = (const float*)d_in[5];
    const float* W2  = (const float*)d_in[6];
    const float* b2  = (const float*)d_in[7];
    const float* g2  = (const float*)d_in[8];
    const float* be2 = (const float*)d_in[9];
    float* out = (float*)d_out;

    const int N = in_sizes[0] / 64;   // 100000
    const int E = in_sizes[1] / 2;    // 1250000

    // workspace layout (floats)
    float* ws    = (float*)d_ws;
    float* h0    = ws;                        // N*64
    float* h1    = h0 + (long)N * 64;         // N*128
    float* W2p   = h1 + (long)N * 128;        // 128*128
    float* b2p   = W2p + 128 * 128;           // 128
    float* stats = b2p + 128;                 // 512: sum1,sq1,sum2,sq2
    float* ac    = stats + 512;               // 256: a2,c2

    // CSR arrays alias h1 (nbr dead before GEMM1 writes h1)
    int* deg  = (int*)h1;                     // N
    int* offs = deg + N;                      // N+1
    int* head = offs + N + 1;                 // N
    int* nbr  = head + N;                     // E
    int* bsum = nbr + E;                      // <=1024
    int* bpre = bsum + 1024;                  // <=1024

    const float invN = 1.0f / (float)N;
    const int nb = (N + 1023) / 1024;         // scan chunks

    k_zero<<<(N + 255) / 256, 256, 0, stream>>>(deg, stats, N);

    int eBlocks = (E + 255) / 256;
    k_hist<<<eBlocks, 256, 0, stream>>>(ei, deg, E);

    k_scanA<<<nb, 256, 0, stream>>>(deg, bsum, N);
    k_scanB<<<1, 1024, 0, stream>>>(bsum, bpre, offs, nb, N, E);
    k_scanC<<<nb, 256, 0, stream>>>(deg, bpre, offs, head, N);

    k_fill<<<eBlocks, 256, 0, stream>>>(ei, head, nbr, E);

    k_gather<<<(N + 3) / 4, 256, 0, stream>>>((const float4*)x, offs, nbr, (float4*)h0, N);

    int gBlocks = (N + 63) / 64;
    k_gemm_bias_relu<64><<<gBlocks, 256, 0, stream>>>(h0, W1, b1, h1, N);

    k_col_stats<<<512, 256, 0, stream>>>(h1, N, stats, stats + 128);

    k_bn_fold<<<1, 128, 0, stream>>>(stats, g1, be1, W2, b2, W2p, b2p, invN);

    k_gemm_bias_relu<128><<<gBlocks, 256, 0, stream>>>(h1, W2p, b2p, out, N);

    k_col_stats<<<512, 256, 0, stream>>>(out, N, stats + 256, stats + 384);

    k_bn_coeffs<<<1, 128, 0, stream>>>(stats + 256, g2, be2, ac, invN);

    long n4o = (long)N * 128 / 4;
    k_bn_apply<<<(int)((n4o + 255) / 256), 256, 0, stream>>>(out, ac, n4o);
}